// Round 1
// baseline (98.186 us; speedup 1.0000x reference)
//
#include <hip/hip_runtime.h>
#include <hip/hip_bf16.h>

#define B_ 16
#define S_ 512
#define D_ 768
#define E_ 16
#define K_ 4

typedef __attribute__((ext_vector_type(8))) short short8;
typedef __attribute__((ext_vector_type(4))) float f32x4;

// ---------------- K1: column means (partial over s-chunks) + x -> bf16 ----------------
__global__ void k1_mean_cvt(const float* __restrict__ x, __hip_bfloat16* __restrict__ xb,
                            float* __restrict__ partial) {
    int t  = threadIdx.x;
    int dc = blockIdx.x;   // 0..2  (d chunk of 256)
    int b  = blockIdx.y;   // 0..15
    int sc = blockIdx.z;   // 0..7  (s chunk of 64)
    int d  = dc * 256 + t;
    const float*      xp  = x  + ((size_t)b * S_ + (size_t)sc * 64) * D_ + d;
    __hip_bfloat16*   xbp = xb + ((size_t)b * S_ + (size_t)sc * 64) * D_ + d;
    float acc = 0.f;
    #pragma unroll 4
    for (int s = 0; s < 64; ++s) {
        float v = xp[(size_t)s * D_];
        acc += v;
        xbp[(size_t)s * D_] = __float2bfloat16(v);
    }
    partial[((size_t)sc * B_ + b) * D_ + d] = acc;  // deterministic, no atomics
}

// ---------------- K2: gating: logits, softmax gates, top-k thresholds, load, loss ------
__global__ void k2_gating(const float* __restrict__ partial,
                          const float* __restrict__ noise,
                          const float* __restrict__ w_gate,
                          const float* __restrict__ w_noise,
                          const float* __restrict__ thr_ptr,
                          float* __restrict__ gates_out,
                          float* __restrict__ loss_out) {
    __shared__ float xm[B_][D_];          // 48 KB
    __shared__ float s_noisy[B_][E_];
    __shared__ float s_clean[B_][E_];
    __shared__ float s_std[B_][E_];
    __shared__ float s_thr_in[B_];
    __shared__ float s_thr_out[B_];
    __shared__ float s_gate[B_][E_];
    __shared__ float s_imp[E_];
    __shared__ float s_load[E_];

    int t = threadIdx.x;              // 256 threads = (b,e) pairs
    // reduce the 8 s-chunk partials -> mean
    for (int idx = t; idx < B_ * D_; idx += 256) {
        float s = 0.f;
        #pragma unroll
        for (int c = 0; c < 8; ++c) s += partial[c * B_ * D_ + idx];
        xm[idx / D_][idx % D_] = s * (1.0f / S_);
    }
    __syncthreads();

    int b = t >> 4, e = t & 15;
    float cl = 0.f, nz = 0.f;
    for (int d = 0; d < D_; ++d) {
        float xv = xm[b][d];
        cl += xv * w_gate[d * E_ + e];
        nz += xv * w_noise[d * E_ + e];
    }
    float sp     = fmaxf(nz, 0.f) + log1pf(expf(-fabsf(nz)));  // softplus
    float stddev = sp + 0.01f;                                  // + NOISE_EPS
    float noisy  = cl + noise[b * E_ + e] * stddev;
    s_clean[b][e] = cl;
    s_std[b][e]   = stddev;
    s_noisy[b][e] = noisy;
    __syncthreads();

    // rank within the row (strict total order via index tie-break)
    int rank = 0;
    for (int j = 0; j < E_; ++j) {
        float vj = s_noisy[b][j];
        if (vj > noisy || (vj == noisy && j < e)) rank++;
    }
    if (rank == K_)     s_thr_in[b]  = noisy;   // (K+1)-th largest
    if (rank == K_ - 1) s_thr_out[b] = noisy;   // K-th largest

    // softmax over the row
    float mx = -1e30f;
    for (int j = 0; j < E_; ++j) mx = fmaxf(mx, s_noisy[b][j]);
    float den = 0.f;
    for (int j = 0; j < E_; ++j) den += expf(s_noisy[b][j] - mx);
    float gate = expf(noisy - mx) / den;
    float sig  = 1.f / (1.f + expf(-thr_ptr[0]));
    float sg   = fmaxf(gate - sig, 0.f);        // gates>0 so sign()*relu(|.|-sig) == this
    s_gate[b][e] = sg;
    gates_out[b * E_ + e] = sg;
    __syncthreads();

    if (t < E_) {
        float imp = 0.f, ld = 0.f;
        for (int bb = 0; bb < B_; ++bb) {
            imp += s_gate[bb][t];
            float ti = s_thr_in[bb], to = s_thr_out[bb];
            float c2 = s_clean[bb][t], sd = s_std[bb][t], nl = s_noisy[bb][t];
            float z  = (nl > ti) ? (c2 - ti) / sd : (c2 - to) / sd;
            ld += 0.5f * erfcf(-z * 0.70710678118654752f);   // Phi(z)
        }
        s_imp[t]  = imp;
        s_load[t] = ld;
    }
    __syncthreads();

    if (t == 0) {
        float m1 = 0.f, m2 = 0.f;
        for (int j = 0; j < E_; ++j) { m1 += s_imp[j]; m2 += s_load[j]; }
        m1 /= E_; m2 /= E_;
        float v1 = 0.f, v2 = 0.f;
        for (int j = 0; j < E_; ++j) {
            float a = s_imp[j]  - m1; v1 += a * a;
            float c = s_load[j] - m2; v2 += c * c;
        }
        v1 /= (E_ - 1); v2 /= (E_ - 1);                      // ddof=1
        loss_out[0] = (v1 / (m1 * m1 + 1e-10f) + v2 / (m2 * m2 + 1e-10f)) * 0.01f;
    }
}

// ---------------- K3: Wb[b,o,i] = sum_e g[b,e] * w[e,o,i]  (bf16 out) -------------------
__global__ void k3_wb(const float* __restrict__ gates, const float* __restrict__ weight,
                      __hip_bfloat16* __restrict__ wb) {
    __shared__ float g[B_ * E_];
    int t = threadIdx.x;
    g[t] = gates[t];
    __syncthreads();

    size_t base = ((size_t)blockIdx.x * 256 + t) * 4;  // element index into D*D (float4)
    float4 acc[B_];
    #pragma unroll
    for (int b = 0; b < B_; ++b) acc[b] = make_float4(0.f, 0.f, 0.f, 0.f);

    #pragma unroll
    for (int e = 0; e < E_; ++e) {
        float4 w4 = *(const float4*)(weight + (size_t)e * D_ * D_ + base);
        #pragma unroll
        for (int b = 0; b < B_; ++b) {
            float ge = g[b * E_ + e];
            acc[b].x += ge * w4.x; acc[b].y += ge * w4.y;
            acc[b].z += ge * w4.z; acc[b].w += ge * w4.w;
        }
    }
    #pragma unroll
    for (int b = 0; b < B_; ++b) {
        __hip_bfloat16 h0 = __float2bfloat16(acc[b].x);
        __hip_bfloat16 h1 = __float2bfloat16(acc[b].y);
        __hip_bfloat16 h2 = __float2bfloat16(acc[b].z);
        __hip_bfloat16 h3 = __float2bfloat16(acc[b].w);
        ushort4 pk;
        pk.x = *(unsigned short*)&h0; pk.y = *(unsigned short*)&h1;
        pk.z = *(unsigned short*)&h2; pk.w = *(unsigned short*)&h3;
        *(ushort4*)((unsigned short*)wb + (size_t)b * D_ * D_ + base) = pk;
    }
}

// ---------------- K3b: expert bias: eb[b,o] = sum_e g[b,e]*bias[e,o] --------------------
__global__ void k3b_ebias(const float* __restrict__ gates, const float* __restrict__ bias,
                          float* __restrict__ ebias) {
    int idx = blockIdx.x * 256 + threadIdx.x;  // 0..B*D-1
    int b = idx / D_, o = idx % D_;
    float acc = 0.f;
    #pragma unroll
    for (int e = 0; e < E_; ++e) acc += gates[b * E_ + e] * bias[e * D_ + o];
    ebias[idx] = acc;
}

// ---------------- K4: batched GEMM y[b] = xb[b] @ Wb[b]^T + eb[b] (bf16 MFMA) -----------
#define BM 128
#define BN 128
#define BK 64
#define LDP 72   // padded LDS row stride (bf16): 144 B -> 2-way bank aliasing (free)

__global__ __launch_bounds__(256) void k4_gemm(const __hip_bfloat16* __restrict__ xb,
                                               const __hip_bfloat16* __restrict__ wbm,
                                               const float* __restrict__ ebias,
                                               float* __restrict__ y) {
    __shared__ __hip_bfloat16 As[BM * LDP];
    __shared__ __hip_bfloat16 Bs[BN * LDP];

    int t  = threadIdx.x;
    int bn = blockIdx.x;   // 0..5
    int bm = blockIdx.y;   // 0..3
    int b  = blockIdx.z;   // 0..15

    const __hip_bfloat16* xp = xb  + (size_t)b * S_ * D_ + (size_t)(bm * BM) * D_;
    const __hip_bfloat16* wp = wbm + (size_t)b * D_ * D_ + (size_t)(bn * BN) * D_;

    int wave = t >> 6, lane = t & 63;
    int wm = wave >> 1, wn = wave & 1;         // 2x2 waves, each 64x64 out
    int lrow = lane & 15;
    int lk   = (lane >> 4) << 3;               // 0,8,16,24

    f32x4 zero4 = {0.f, 0.f, 0.f, 0.f};
    f32x4 acc[4][4];
    #pragma unroll
    for (int m = 0; m < 4; ++m)
        #pragma unroll
        for (int n = 0; n < 4; ++n) acc[m][n] = zero4;

    int srow   = t >> 3;          // 0..31
    int schunk = (t & 7) * 8;     // 0..56

    for (int k0 = 0; k0 < D_; k0 += BK) {
        __syncthreads();
        #pragma unroll
        for (int p = 0; p < 4; ++p) {
            int r = srow + p * 32;
            short8 va = *(const short8*)(xp + (size_t)r * D_ + k0 + schunk);
            *(short8*)(&As[r * LDP + schunk]) = va;
            short8 vb = *(const short8*)(wp + (size_t)r * D_ + k0 + schunk);
            *(short8*)(&Bs[r * LDP + schunk]) = vb;
        }
        __syncthreads();

        #pragma unroll
        for (int kk = 0; kk < BK; kk += 32) {
            short8 afr[4], bfr[4];
            #pragma unroll
            for (int m = 0; m < 4; ++m)
                afr[m] = *(const short8*)(&As[(wm * 64 + m * 16 + lrow) * LDP + kk + lk]);
            #pragma unroll
            for (int n = 0; n < 4; ++n)
                bfr[n] = *(const short8*)(&Bs[(wn * 64 + n * 16 + lrow) * LDP + kk + lk]);
            #pragma unroll
            for (int m = 0; m < 4; ++m)
                #pragma unroll
                for (int n = 0; n < 4; ++n)
                    acc[m][n] = __builtin_amdgcn_mfma_f32_16x16x32_bf16(afr[m], bfr[n], acc[m][n], 0, 0, 0);
        }
    }

    float* yp = y + (size_t)b * S_ * D_ + (size_t)(bm * BM) * D_ + bn * BN;
    const float* ep = ebias + (size_t)b * D_ + bn * BN;
    int crow = (lane >> 4) * 4;   // + j
    int ccol = lane & 15;
    #pragma unroll
    for (int n = 0; n < 4; ++n) {
        float eb = ep[wn * 64 + n * 16 + ccol];
        #pragma unroll
        for (int m = 0; m < 4; ++m) {
            #pragma unroll
            for (int j = 0; j < 4; ++j) {
                yp[(size_t)(wm * 64 + m * 16 + crow + j) * D_ + wn * 64 + n * 16 + ccol] =
                    acc[m][n][j] + eb;
            }
        }
    }
}

// -------------------------------------------------------------------------------------
extern "C" void kernel_launch(void* const* d_in, const int* in_sizes, int n_in,
                              void* d_out, int out_size, void* d_ws, size_t ws_size,
                              hipStream_t stream) {
    const float* x       = (const float*)d_in[0];
    const float* noise   = (const float*)d_in[1];
    const float* w_gate  = (const float*)d_in[2];
    const float* w_noise = (const float*)d_in[3];
    const float* thr     = (const float*)d_in[4];
    const float* weight  = (const float*)d_in[5];
    const float* bias    = (const float*)d_in[6];
    float* out = (float*)d_out;   // y [B*S*D] then loss [1]

    char* ws = (char*)d_ws;
    // workspace layout (all 16B-aligned), total ~30.4 MB
    float*          partial = (float*)(ws + 0);              //  8*B*D f32   = 393216 B
    float*          gates   = (float*)(ws + 393216);         //  B*E  f32    = 1024 B
    float*          ebias   = (float*)(ws + 394240);         //  B*D  f32    = 49152 B
    __hip_bfloat16* xb      = (__hip_bfloat16*)(ws + 443392);    // B*S*D bf16 = 12582912 B
    __hip_bfloat16* wb      = (__hip_bfloat16*)(ws + 13026304);  // B*D*D bf16 = 18874368 B

    k1_mean_cvt<<<dim3(3, 16, 8), 256, 0, stream>>>(x, xb, partial);
    k2_gating<<<1, 256, 0, stream>>>(partial, noise, w_gate, w_noise, thr, gates,
                                     out + (size_t)B_ * S_ * D_);
    k3_wb<<<(D_ * D_) / 1024, 256, 0, stream>>>(gates, weight, wb);
    k3b_ebias<<<(B_ * D_) / 256, 256, 0, stream>>>(gates, bias, ebias);
    k4_gemm<<<dim3(D_ / BN, S_ / BM, B_), 256, 0, stream>>>(xb, wb, ebias, out);
}

// Round 2
// 77.850 us; speedup vs baseline: 1.2612x; 1.2612x over previous
//
#include <hip/hip_runtime.h>
#include <hip/hip_bf16.h>

#define B_ 16
#define S_ 512
#define D_ 768
#define E_ 16
#define K_ 4

typedef __attribute__((ext_vector_type(8))) short short8;
typedef __attribute__((ext_vector_type(4))) float f32x4;

// ---------------- K1: column means (partial over s-chunks) + x -> bf16 ----------------
__global__ void k1_mean_cvt(const float* __restrict__ x, __hip_bfloat16* __restrict__ xb,
                            float* __restrict__ partial) {
    int t  = threadIdx.x;
    int dc = blockIdx.x;   // 0..2  (d chunk of 256)
    int b  = blockIdx.y;   // 0..15
    int sc = blockIdx.z;   // 0..7  (s chunk of 64)
    int d  = dc * 256 + t;
    const float*      xp  = x  + ((size_t)b * S_ + (size_t)sc * 64) * D_ + d;
    __hip_bfloat16*   xbp = xb + ((size_t)b * S_ + (size_t)sc * 64) * D_ + d;
    float acc = 0.f;
    #pragma unroll 4
    for (int s = 0; s < 64; ++s) {
        float v = xp[(size_t)s * D_];
        acc += v;
        xbp[(size_t)s * D_] = __float2bfloat16(v);
    }
    partial[((size_t)sc * B_ + b) * D_ + d] = acc;  // deterministic, no atomics
}

// ---------------- K2a: per-batch gating (16 blocks, d-parallel dot products) -----------
__global__ void k2a_logits(const float* __restrict__ partial,
                           const float* __restrict__ noise,
                           const float* __restrict__ w_gate,
                           const float* __restrict__ w_noise,
                           const float* __restrict__ thr_ptr,
                           float* __restrict__ gates_out,
                           float* __restrict__ clean_out,
                           float* __restrict__ std_out,
                           float* __restrict__ noisy_out,
                           float* __restrict__ thrin_out,
                           float* __restrict__ throut_out) {
    __shared__ float xm[D_];
    __shared__ float red[2][16][17];   // [cl/nz][slice][e] (+1 pad)
    __shared__ float s_noisy[E_];

    int b = blockIdx.x, t = threadIdx.x;

    // reduce the 8 s-chunk partials -> mean (768 d's over 256 threads)
    for (int d = t; d < D_; d += 256) {
        float s = 0.f;
        #pragma unroll
        for (int c = 0; c < 8; ++c) s += partial[((size_t)c * B_ + b) * D_ + d];
        xm[d] = s * (1.0f / S_);
    }
    __syncthreads();

    // partial dot products: thread = (e, slice of 48 d's)
    int e = t & 15, sl = t >> 4;
    const float* wg = w_gate  + (size_t)sl * 48 * E_ + e;
    const float* wn = w_noise + (size_t)sl * 48 * E_ + e;
    float cl = 0.f, nz = 0.f;
    #pragma unroll
    for (int i = 0; i < 48; ++i) {
        float xv = xm[sl * 48 + i];
        cl += xv * wg[(size_t)i * E_];
        nz += xv * wn[(size_t)i * E_];
    }
    red[0][sl][e] = cl;
    red[1][sl][e] = nz;
    __syncthreads();

    if (t < E_) {
        float c2 = 0.f, n2 = 0.f;
        #pragma unroll
        for (int s2 = 0; s2 < 16; ++s2) { c2 += red[0][s2][t]; n2 += red[1][s2][t]; }
        float sp     = fmaxf(n2, 0.f) + log1pf(expf(-fabsf(n2)));  // softplus
        float stddev = sp + 0.01f;                                  // + NOISE_EPS
        float ny     = c2 + noise[b * E_ + t] * stddev;
        s_noisy[t] = ny;
        clean_out[b * E_ + t] = c2;
        std_out[b * E_ + t]   = stddev;
        noisy_out[b * E_ + t] = ny;
    }
    __syncthreads();

    if (t < E_) {
        float ny = s_noisy[t];
        // rank within the row (strict total order via index tie-break)
        int rank = 0;
        #pragma unroll
        for (int j = 0; j < E_; ++j) {
            float vj = s_noisy[j];
            if (vj > ny || (vj == ny && j < t)) rank++;
        }
        if (rank == K_)     thrin_out[b]  = ny;   // (K+1)-th largest
        if (rank == K_ - 1) throut_out[b] = ny;   // K-th largest

        float mx = -1e30f;
        #pragma unroll
        for (int j = 0; j < E_; ++j) mx = fmaxf(mx, s_noisy[j]);
        float den = 0.f;
        #pragma unroll
        for (int j = 0; j < E_; ++j) den += expf(s_noisy[j] - mx);
        float gate = expf(ny - mx) / den;
        float sig  = 1.f / (1.f + expf(-thr_ptr[0]));
        gates_out[b * E_ + t] = fmaxf(gate - sig, 0.f);  // gates>0 so this == sign*relu(|.|-sig)
    }
}

// ---------------- K2b: cross-batch importance/load + cv^2 loss (tiny) ------------------
__global__ void k2b_loss(const float* __restrict__ gates,
                         const float* __restrict__ clean,
                         const float* __restrict__ stdv,
                         const float* __restrict__ noisyv,
                         const float* __restrict__ thrin,
                         const float* __restrict__ throut,
                         float* __restrict__ loss_out) {
    __shared__ float s_imp[E_], s_load[E_];
    int t = threadIdx.x;
    if (t < E_) {
        float imp = 0.f, ld = 0.f;
        #pragma unroll
        for (int bb = 0; bb < B_; ++bb) {
            imp += gates[bb * E_ + t];
            float ti = thrin[bb], to = throut[bb];
            float c2 = clean[bb * E_ + t], sd = stdv[bb * E_ + t], nl = noisyv[bb * E_ + t];
            float z  = (nl > ti) ? (c2 - ti) / sd : (c2 - to) / sd;
            ld += 0.5f * erfcf(-z * 0.70710678118654752f);   // Phi(z)
        }
        s_imp[t]  = imp;
        s_load[t] = ld;
    }
    __syncthreads();
    if (t == 0) {
        float m1 = 0.f, m2 = 0.f;
        #pragma unroll
        for (int j = 0; j < E_; ++j) { m1 += s_imp[j]; m2 += s_load[j]; }
        m1 /= E_; m2 /= E_;
        float v1 = 0.f, v2 = 0.f;
        #pragma unroll
        for (int j = 0; j < E_; ++j) {
            float a = s_imp[j]  - m1; v1 += a * a;
            float c = s_load[j] - m2; v2 += c * c;
        }
        v1 /= (E_ - 1); v2 /= (E_ - 1);                      // ddof=1
        loss_out[0] = (v1 / (m1 * m1 + 1e-10f) + v2 / (m2 * m2 + 1e-10f)) * 0.01f;
    }
}

// ---------------- K3: Wb[b,o,i] = sum_e g[b,e] * w[e,o,i]  (bf16 out) -------------------
__global__ void k3_wb(const float* __restrict__ gates, const float* __restrict__ weight,
                      __hip_bfloat16* __restrict__ wb) {
    __shared__ float g[B_ * E_];
    int t = threadIdx.x;
    g[t] = gates[t];
    __syncthreads();

    size_t base = ((size_t)blockIdx.x * 256 + t) * 4;  // element index into D*D (float4)
    float4 acc[B_];
    #pragma unroll
    for (int b = 0; b < B_; ++b) acc[b] = make_float4(0.f, 0.f, 0.f, 0.f);

    #pragma unroll
    for (int e = 0; e < E_; ++e) {
        float4 w4 = *(const float4*)(weight + (size_t)e * D_ * D_ + base);
        #pragma unroll
        for (int b = 0; b < B_; ++b) {
            float ge = g[b * E_ + e];
            acc[b].x += ge * w4.x; acc[b].y += ge * w4.y;
            acc[b].z += ge * w4.z; acc[b].w += ge * w4.w;
        }
    }
    #pragma unroll
    for (int b = 0; b < B_; ++b) {
        __hip_bfloat16 h0 = __float2bfloat16(acc[b].x);
        __hip_bfloat16 h1 = __float2bfloat16(acc[b].y);
        __hip_bfloat16 h2 = __float2bfloat16(acc[b].z);
        __hip_bfloat16 h3 = __float2bfloat16(acc[b].w);
        ushort4 pk;
        pk.x = *(unsigned short*)&h0; pk.y = *(unsigned short*)&h1;
        pk.z = *(unsigned short*)&h2; pk.w = *(unsigned short*)&h3;
        *(ushort4*)((unsigned short*)wb + (size_t)b * D_ * D_ + base) = pk;
    }
}

// ---------------- K3b: expert bias: eb[b,o] = sum_e g[b,e]*bias[e,o] --------------------
__global__ void k3b_ebias(const float* __restrict__ gates, const float* __restrict__ bias,
                          float* __restrict__ ebias) {
    int idx = blockIdx.x * 256 + threadIdx.x;  // 0..B*D-1
    int b = idx / D_, o = idx % D_;
    float acc = 0.f;
    #pragma unroll
    for (int e = 0; e < E_; ++e) acc += gates[b * E_ + e] * bias[e * D_ + o];
    ebias[idx] = acc;
}

// ---------------- K4: batched GEMM y[b] = xb[b] @ Wb[b]^T + eb[b] (bf16 MFMA) -----------
#define BM 128
#define BN 128
#define BK 64
#define LDP 72   // padded LDS row stride (bf16): 144 B -> 2-way bank aliasing (free)

__global__ __launch_bounds__(256) void k4_gemm(const __hip_bfloat16* __restrict__ xb,
                                               const __hip_bfloat16* __restrict__ wbm,
                                               const float* __restrict__ ebias,
                                               float* __restrict__ y) {
    __shared__ __hip_bfloat16 As[BM * LDP];
    __shared__ __hip_bfloat16 Bs[BN * LDP];

    int t  = threadIdx.x;
    int bn = blockIdx.x;   // 0..5
    int bm = blockIdx.y;   // 0..3
    int b  = blockIdx.z;   // 0..15

    const __hip_bfloat16* xp = xb  + (size_t)b * S_ * D_ + (size_t)(bm * BM) * D_;
    const __hip_bfloat16* wp = wbm + (size_t)b * D_ * D_ + (size_t)(bn * BN) * D_;

    int wave = t >> 6, lane = t & 63;
    int wm = wave >> 1, wn = wave & 1;         // 2x2 waves, each 64x64 out
    int lrow = lane & 15;
    int lk   = (lane >> 4) << 3;               // 0,8,16,24

    f32x4 zero4 = {0.f, 0.f, 0.f, 0.f};
    f32x4 acc[4][4];
    #pragma unroll
    for (int m = 0; m < 4; ++m)
        #pragma unroll
        for (int n = 0; n < 4; ++n) acc[m][n] = zero4;

    int srow   = t >> 3;          // 0..31
    int schunk = (t & 7) * 8;     // 0..56

    for (int k0 = 0; k0 < D_; k0 += BK) {
        __syncthreads();
        #pragma unroll
        for (int p = 0; p < 4; ++p) {
            int r = srow + p * 32;
            short8 va = *(const short8*)(xp + (size_t)r * D_ + k0 + schunk);
            *(short8*)(&As[r * LDP + schunk]) = va;
            short8 vb = *(const short8*)(wp + (size_t)r * D_ + k0 + schunk);
            *(short8*)(&Bs[r * LDP + schunk]) = vb;
        }
        __syncthreads();

        #pragma unroll
        for (int kk = 0; kk < BK; kk += 32) {
            short8 afr[4], bfr[4];
            #pragma unroll
            for (int m = 0; m < 4; ++m)
                afr[m] = *(const short8*)(&As[(wm * 64 + m * 16 + lrow) * LDP + kk + lk]);
            #pragma unroll
            for (int n = 0; n < 4; ++n)
                bfr[n] = *(const short8*)(&Bs[(wn * 64 + n * 16 + lrow) * LDP + kk + lk]);
            #pragma unroll
            for (int m = 0; m < 4; ++m)
                #pragma unroll
                for (int n = 0; n < 4; ++n)
                    acc[m][n] = __builtin_amdgcn_mfma_f32_16x16x32_bf16(afr[m], bfr[n], acc[m][n], 0, 0, 0);
        }
    }

    float* yp = y + (size_t)b * S_ * D_ + (size_t)(bm * BM) * D_ + bn * BN;
    const float* ep = ebias + (size_t)b * D_ + bn * BN;
    int crow = (lane >> 4) * 4;   // + j
    int ccol = lane & 15;
    #pragma unroll
    for (int n = 0; n < 4; ++n) {
        float eb = ep[wn * 64 + n * 16 + ccol];
        #pragma unroll
        for (int m = 0; m < 4; ++m) {
            #pragma unroll
            for (int j = 0; j < 4; ++j) {
                yp[(size_t)(wm * 64 + m * 16 + crow + j) * D_ + wn * 64 + n * 16 + ccol] =
                    acc[m][n][j] + eb;
            }
        }
    }
}

// -------------------------------------------------------------------------------------
extern "C" void kernel_launch(void* const* d_in, const int* in_sizes, int n_in,
                              void* d_out, int out_size, void* d_ws, size_t ws_size,
                              hipStream_t stream) {
    const float* x       = (const float*)d_in[0];
    const float* noise   = (const float*)d_in[1];
    const float* w_gate  = (const float*)d_in[2];
    const float* w_noise = (const float*)d_in[3];
    const float* thr     = (const float*)d_in[4];
    const float* weight  = (const float*)d_in[5];
    const float* bias    = (const float*)d_in[6];
    float* out = (float*)d_out;   // y [B*S*D] then loss [1]

    char* ws = (char*)d_ws;
    // workspace layout (all 16B-aligned), total ~30.4 MB
    float*          partial = (float*)(ws + 0);              //  8*B*D f32   = 393216 B
    float*          gates   = (float*)(ws + 393216);         //  B*E  f32    = 1024 B
    float*          clean   = (float*)(ws + 394240);         //  B*E  f32    = 1024 B
    float*          stdv    = (float*)(ws + 395264);         //  B*E  f32    = 1024 B
    float*          noisyv  = (float*)(ws + 396288);         //  B*E  f32    = 1024 B
    float*          thrin   = (float*)(ws + 397312);         //  B    f32    = 64 B
    float*          throut  = (float*)(ws + 397376);         //  B    f32    = 64 B
    float*          ebias   = (float*)(ws + 397440);         //  B*D  f32    = 49152 B
    __hip_bfloat16* xb      = (__hip_bfloat16*)(ws + 446592);    // B*S*D bf16 = 12582912 B
    __hip_bfloat16* wb      = (__hip_bfloat16*)(ws + 13029504);  // B*D*D bf16 = 18874368 B

    k1_mean_cvt<<<dim3(3, 16, 8), 256, 0, stream>>>(x, xb, partial);
    k2a_logits<<<16, 256, 0, stream>>>(partial, noise, w_gate, w_noise, thr, gates,
                                       clean, stdv, noisyv, thrin, throut);
    k2b_loss<<<1, 64, 0, stream>>>(gates, clean, stdv, noisyv, thrin, throut,
                                   out + (size_t)B_ * S_ * D_);
    k3_wb<<<(D_ * D_) / 1024, 256, 0, stream>>>(gates, weight, wb);
    k3b_ebias<<<(B_ * D_) / 256, 256, 0, stream>>>(gates, bias, ebias);
    k4_gemm<<<dim3(D_ / BN, S_ / BM, B_), 256, 0, stream>>>(xb, wb, ebias, out);
}

// Round 3
// 76.485 us; speedup vs baseline: 1.2837x; 1.0178x over previous
//
#include <hip/hip_runtime.h>
#include <hip/hip_bf16.h>

#define B_ 16
#define S_ 512
#define D_ 768
#define E_ 16
#define K_ 4

typedef __attribute__((ext_vector_type(8))) short short8;
typedef __attribute__((ext_vector_type(4))) float f32x4;

#define GLOAD16(gp, lp)                                             \
    __builtin_amdgcn_global_load_lds(                               \
        (const __attribute__((address_space(1))) void*)(gp),        \
        (__attribute__((address_space(3))) void*)(lp), 16, 0, 0)

// ---------------- K1: column means (16 s-chunks) + x -> bf16, vectorized ---------------
// grid (B, 16), block 192: thread owns 4 consecutive d's, walks 32 s-rows.
__global__ void k1_mean_cvt(const float* __restrict__ x, __hip_bfloat16* __restrict__ xb,
                            float* __restrict__ partial) {
    int t  = threadIdx.x;          // 0..191
    int b  = blockIdx.x;           // 0..15
    int sc = blockIdx.y;           // 0..15 (s chunk of 32)
    size_t rowbase = ((size_t)b * S_ + (size_t)sc * 32) * D_ + t * 4;

    float4 acc = make_float4(0.f, 0.f, 0.f, 0.f);
    #pragma unroll 8
    for (int s = 0; s < 32; ++s) {
        float4 v = *(const float4*)(x + rowbase + (size_t)s * D_);
        acc.x += v.x; acc.y += v.y; acc.z += v.z; acc.w += v.w;
        __hip_bfloat16 h0 = __float2bfloat16(v.x);
        __hip_bfloat16 h1 = __float2bfloat16(v.y);
        __hip_bfloat16 h2 = __float2bfloat16(v.z);
        __hip_bfloat16 h3 = __float2bfloat16(v.w);
        ushort4 pk;
        pk.x = *(unsigned short*)&h0; pk.y = *(unsigned short*)&h1;
        pk.z = *(unsigned short*)&h2; pk.w = *(unsigned short*)&h3;
        *(ushort4*)((unsigned short*)xb + rowbase + (size_t)s * D_) = pk;
    }
    *(float4*)(partial + ((size_t)sc * B_ + b) * D_ + t * 4) = acc;
}

// ---------------- K2a: per-batch gating (16 blocks, d-parallel dot products) -----------
__global__ void k2a_logits(const float* __restrict__ partial,
                           const float* __restrict__ noise,
                           const float* __restrict__ w_gate,
                           const float* __restrict__ w_noise,
                           const float* __restrict__ thr_ptr,
                           float* __restrict__ gates_out,
                           float* __restrict__ clean_out,
                           float* __restrict__ std_out,
                           float* __restrict__ noisy_out,
                           float* __restrict__ thrin_out,
                           float* __restrict__ throut_out) {
    __shared__ float xm[D_];
    __shared__ float red[2][16][17];   // [cl/nz][slice][e] (+1 pad)
    __shared__ float s_noisy[E_];

    int b = blockIdx.x, t = threadIdx.x;

    // reduce the 16 s-chunk partials -> mean
    for (int d = t; d < D_; d += 256) {
        float s = 0.f;
        #pragma unroll
        for (int c = 0; c < 16; ++c) s += partial[((size_t)c * B_ + b) * D_ + d];
        xm[d] = s * (1.0f / S_);
    }
    __syncthreads();

    // partial dot products: thread = (e, slice of 48 d's)
    int e = t & 15, sl = t >> 4;
    const float* wg = w_gate  + (size_t)sl * 48 * E_ + e;
    const float* wn = w_noise + (size_t)sl * 48 * E_ + e;
    float cl = 0.f, nz = 0.f;
    #pragma unroll
    for (int i = 0; i < 48; ++i) {
        float xv = xm[sl * 48 + i];
        cl += xv * wg[(size_t)i * E_];
        nz += xv * wn[(size_t)i * E_];
    }
    red[0][sl][e] = cl;
    red[1][sl][e] = nz;
    __syncthreads();

    if (t < E_) {
        float c2 = 0.f, n2 = 0.f;
        #pragma unroll
        for (int s2 = 0; s2 < 16; ++s2) { c2 += red[0][s2][t]; n2 += red[1][s2][t]; }
        float sp     = fmaxf(n2, 0.f) + log1pf(expf(-fabsf(n2)));  // softplus
        float stddev = sp + 0.01f;                                  // + NOISE_EPS
        float ny     = c2 + noise[b * E_ + t] * stddev;
        s_noisy[t] = ny;
        clean_out[b * E_ + t] = c2;
        std_out[b * E_ + t]   = stddev;
        noisy_out[b * E_ + t] = ny;
    }
    __syncthreads();

    if (t < E_) {
        float ny = s_noisy[t];
        // rank within the row (strict total order via index tie-break)
        int rank = 0;
        #pragma unroll
        for (int j = 0; j < E_; ++j) {
            float vj = s_noisy[j];
            if (vj > ny || (vj == ny && j < t)) rank++;
        }
        if (rank == K_)     thrin_out[b]  = ny;   // (K+1)-th largest
        if (rank == K_ - 1) throut_out[b] = ny;   // K-th largest

        float mx = -1e30f;
        #pragma unroll
        for (int j = 0; j < E_; ++j) mx = fmaxf(mx, s_noisy[j]);
        float den = 0.f;
        #pragma unroll
        for (int j = 0; j < E_; ++j) den += expf(s_noisy[j] - mx);
        float gate = expf(ny - mx) / den;
        float sig  = 1.f / (1.f + expf(-thr_ptr[0]));
        gates_out[b * E_ + t] = fmaxf(gate - sig, 0.f);  // gates>0 so == sign*relu(|.|-sig)
    }
}

// ---------------- K2b: cross-batch importance/load + cv^2 loss (tiny) ------------------
__global__ void k2b_loss(const float* __restrict__ gates,
                         const float* __restrict__ clean,
                         const float* __restrict__ stdv,
                         const float* __restrict__ noisyv,
                         const float* __restrict__ thrin,
                         const float* __restrict__ throut,
                         float* __restrict__ loss_out) {
    __shared__ float s_imp[E_], s_load[E_];
    int t = threadIdx.x;
    if (t < E_) {
        float imp = 0.f, ld = 0.f;
        #pragma unroll
        for (int bb = 0; bb < B_; ++bb) {
            imp += gates[bb * E_ + t];
            float ti = thrin[bb], to = throut[bb];
            float c2 = clean[bb * E_ + t], sd = stdv[bb * E_ + t], nl = noisyv[bb * E_ + t];
            float z  = (nl > ti) ? (c2 - ti) / sd : (c2 - to) / sd;
            ld += 0.5f * erfcf(-z * 0.70710678118654752f);   // Phi(z)
        }
        s_imp[t]  = imp;
        s_load[t] = ld;
    }
    __syncthreads();
    if (t == 0) {
        float m1 = 0.f, m2 = 0.f;
        #pragma unroll
        for (int j = 0; j < E_; ++j) { m1 += s_imp[j]; m2 += s_load[j]; }
        m1 /= E_; m2 /= E_;
        float v1 = 0.f, v2 = 0.f;
        #pragma unroll
        for (int j = 0; j < E_; ++j) {
            float a = s_imp[j]  - m1; v1 += a * a;
            float c = s_load[j] - m2; v2 += c * c;
        }
        v1 /= (E_ - 1); v2 /= (E_ - 1);                      // ddof=1
        loss_out[0] = (v1 / (m1 * m1 + 1e-10f) + v2 / (m2 * m2 + 1e-10f)) * 0.01f;
    }
}

// ---------------- K3: Wb mix (blocks 0..575) + expert bias (blocks 576..623) -----------
__global__ void k3_wb(const float* __restrict__ gates, const float* __restrict__ weight,
                      const float* __restrict__ bias,
                      __hip_bfloat16* __restrict__ wb, float* __restrict__ ebias) {
    __shared__ float g[B_ * E_];
    int t = threadIdx.x;
    g[t] = gates[t];
    __syncthreads();

    if (blockIdx.x >= 576) {                 // bias-mix tail blocks
        int idx = (blockIdx.x - 576) * 256 + t;   // 0..12287 = B*D
        int b = idx / D_, o = idx % D_;
        float acc = 0.f;
        #pragma unroll
        for (int e = 0; e < E_; ++e) acc += g[b * E_ + e] * bias[e * D_ + o];
        ebias[idx] = acc;
        return;
    }

    size_t base = ((size_t)blockIdx.x * 256 + t) * 4;  // element index into D*D (float4)
    float4 acc[B_];
    #pragma unroll
    for (int b = 0; b < B_; ++b) acc[b] = make_float4(0.f, 0.f, 0.f, 0.f);

    #pragma unroll
    for (int e = 0; e < E_; ++e) {
        float4 w4 = *(const float4*)(weight + (size_t)e * D_ * D_ + base);
        #pragma unroll
        for (int b = 0; b < B_; ++b) {
            float ge = g[b * E_ + e];
            acc[b].x += ge * w4.x; acc[b].y += ge * w4.y;
            acc[b].z += ge * w4.z; acc[b].w += ge * w4.w;
        }
    }
    #pragma unroll
    for (int b = 0; b < B_; ++b) {
        __hip_bfloat16 h0 = __float2bfloat16(acc[b].x);
        __hip_bfloat16 h1 = __float2bfloat16(acc[b].y);
        __hip_bfloat16 h2 = __float2bfloat16(acc[b].z);
        __hip_bfloat16 h3 = __float2bfloat16(acc[b].w);
        ushort4 pk;
        pk.x = *(unsigned short*)&h0; pk.y = *(unsigned short*)&h1;
        pk.z = *(unsigned short*)&h2; pk.w = *(unsigned short*)&h3;
        *(ushort4*)((unsigned short*)wb + (size_t)b * D_ * D_ + base) = pk;
    }
}

// ---------------- K4: batched GEMM y[b] = xb[b] @ Wb[b]^T + eb[b] (m97 structure) -------
#define BM 128
#define BN 128
#define BK 64
#define NT (D_ / BK)   // 12 K-tiles

__global__ __launch_bounds__(256) void k4_gemm(const __hip_bfloat16* __restrict__ xb,
                                               const __hip_bfloat16* __restrict__ wbm,
                                               const float* __restrict__ ebias,
                                               float* __restrict__ y) {
    // double-buffered LINEAR LDS (required by global_load_lds): 64 KB total
    __shared__ __hip_bfloat16 As[2][BM][BK];
    __shared__ __hip_bfloat16 Bs[2][BN][BK];

    int t  = threadIdx.x;
    int bn = blockIdx.x;   // 0..5
    int bm = blockIdx.y;   // 0..3
    int b  = blockIdx.z;   // 0..15

    const __hip_bfloat16* xp = xb  + (size_t)b * S_ * D_ + (size_t)(bm * BM) * D_;
    const __hip_bfloat16* wp = wbm + (size_t)b * D_ * D_ + (size_t)(bn * BN) * D_;

    int wave = t >> 6, lane = t & 63;
    int wm = wave >> 1, wn = wave & 1;         // 2x2 waves, each 64x64 out
    int lrow = lane & 15;
    int lk   = (lane >> 4) << 3;               // 0,8,16,24

    // staging lane geometry: one gload covers 8 rows x 64 cols (1024B), lane l ->
    // LDS base + l*16B  ==  row (l>>3), byte-col (l&7)*16  of the 8-row group
    int lr = lane >> 3;          // 0..7
    int lc = (lane & 7) * 8;     // element col 0..56

    f32x4 zero4 = {0.f, 0.f, 0.f, 0.f};
    f32x4 acc[4][4];
    #pragma unroll
    for (int m = 0; m < 4; ++m)
        #pragma unroll
        for (int n = 0; n < 4; ++n) acc[m][n] = zero4;

    #define STAGE(buf, k0)                                                          \
        do {                                                                        \
            _Pragma("unroll")                                                       \
            for (int i = 0; i < 4; ++i) {                                           \
                int r = wave * 32 + i * 8;                                          \
                GLOAD16(xp + (size_t)(r + lr) * D_ + (k0) + lc, &As[buf][r][0]);    \
                GLOAD16(wp + (size_t)(r + lr) * D_ + (k0) + lc, &Bs[buf][r][0]);    \
            }                                                                       \
        } while (0)

    #define COMPUTE(buf)                                                            \
        do {                                                                        \
            _Pragma("unroll")                                                       \
            for (int kk = 0; kk < BK; kk += 32) {                                   \
                short8 afr[4], bfr[4];                                              \
                _Pragma("unroll")                                                   \
                for (int m = 0; m < 4; ++m)                                         \
                    afr[m] = *(const short8*)(&As[buf][wm * 64 + m * 16 + lrow][kk + lk]); \
                _Pragma("unroll")                                                   \
                for (int n = 0; n < 4; ++n)                                         \
                    bfr[n] = *(const short8*)(&Bs[buf][wn * 64 + n * 16 + lrow][kk + lk]); \
                _Pragma("unroll")                                                   \
                for (int m = 0; m < 4; ++m)                                         \
                    _Pragma("unroll")                                               \
                    for (int n = 0; n < 4; ++n)                                     \
                        acc[m][n] = __builtin_amdgcn_mfma_f32_16x16x32_bf16(        \
                            afr[m], bfr[n], acc[m][n], 0, 0, 0);                    \
            }                                                                       \
        } while (0)

    STAGE(0, 0);
    __syncthreads();                       // implicit vmcnt(0) drain -> buf0 ready
    int cur = 0;
    for (int kt = 0; kt < NT - 1; ++kt) {
        STAGE(cur ^ 1, (kt + 1) * BK);     // prefetch next tile (in flight during MFMA)
        COMPUTE(cur);
        __syncthreads();                   // drains vmcnt -> next buffer ready
        cur ^= 1;
    }
    COMPUTE(cur);

    float* yp = y + (size_t)b * S_ * D_ + (size_t)(bm * BM) * D_ + bn * BN;
    const float* ep = ebias + (size_t)b * D_ + bn * BN;
    int crow = (lane >> 4) * 4;   // + j
    int ccol = lane & 15;
    #pragma unroll
    for (int n = 0; n < 4; ++n) {
        float eb = ep[wn * 64 + n * 16 + ccol];
        #pragma unroll
        for (int m = 0; m < 4; ++m) {
            #pragma unroll
            for (int j = 0; j < 4; ++j) {
                yp[(size_t)(wm * 64 + m * 16 + crow + j) * D_ + wn * 64 + n * 16 + ccol] =
                    acc[m][n][j] + eb;
            }
        }
    }
    #undef STAGE
    #undef COMPUTE
}

// -------------------------------------------------------------------------------------
extern "C" void kernel_launch(void* const* d_in, const int* in_sizes, int n_in,
                              void* d_out, int out_size, void* d_ws, size_t ws_size,
                              hipStream_t stream) {
    const float* x       = (const float*)d_in[0];
    const float* noise   = (const float*)d_in[1];
    const float* w_gate  = (const float*)d_in[2];
    const float* w_noise = (const float*)d_in[3];
    const float* thr     = (const float*)d_in[4];
    const float* weight  = (const float*)d_in[5];
    const float* bias    = (const float*)d_in[6];
    float* out = (float*)d_out;   // y [B*S*D] then loss [1]

    char* ws = (char*)d_ws;
    // workspace layout (16B-aligned), total ~32.3 MB
    float*          partial = (float*)(ws + 0);               // 16*B*D f32 = 786432 B
    float*          gates   = (float*)(ws + 786432);          // B*E f32
    float*          clean   = (float*)(ws + 787456);          // B*E f32
    float*          stdv    = (float*)(ws + 788480);          // B*E f32
    float*          noisyv  = (float*)(ws + 789504);          // B*E f32
    float*          thrin   = (float*)(ws + 790528);          // B f32
    float*          throut  = (float*)(ws + 790592);          // B f32
    float*          ebias   = (float*)(ws + 790656);          // B*D f32 = 49152 B
    __hip_bfloat16* xb      = (__hip_bfloat16*)(ws + 839808);     // B*S*D bf16 = 12582912 B
    __hip_bfloat16* wb      = (__hip_bfloat16*)(ws + 13422720);   // B*D*D bf16 = 18874368 B

    k1_mean_cvt<<<dim3(B_, 16), 192, 0, stream>>>(x, xb, partial);
    k2a_logits<<<16, 256, 0, stream>>>(partial, noise, w_gate, w_noise, thr, gates,
                                       clean, stdv, noisyv, thrin, throut);
    k2b_loss<<<1, 64, 0, stream>>>(gates, clean, stdv, noisyv, thrin, throut,
                                   out + (size_t)B_ * S_ * D_);
    k3_wb<<<576 + (B_ * D_) / 256, 256, 0, stream>>>(gates, weight, bias, wb, ebias);
    k4_gemm<<<dim3(D_ / BN, S_ / BM, B_), 256, 0, stream>>>(xb, wb, ebias, out);
}

// Round 4
// 59.027 us; speedup vs baseline: 1.6634x; 1.2958x over previous
//
#include <hip/hip_runtime.h>
#include <hip/hip_bf16.h>

#define B_ 16
#define S_ 512
#define D_ 768
#define E_ 16
#define K_ 4

typedef __attribute__((ext_vector_type(8))) short short8;
typedef __attribute__((ext_vector_type(4))) float f32x4;

#define GLOAD16(gp, lp)                                             \
    __builtin_amdgcn_global_load_lds(                               \
        (const __attribute__((address_space(1))) void*)(gp),        \
        (__attribute__((address_space(3))) void*)(lp), 16, 0, 0)

// ---------------- K1: column means (16 s-chunks) + x -> bf16, vectorized ---------------
__global__ void k1_mean_cvt(const float* __restrict__ x, __hip_bfloat16* __restrict__ xb,
                            float* __restrict__ partial) {
    int t  = threadIdx.x;          // 0..191
    int b  = blockIdx.x;           // 0..15
    int sc = blockIdx.y;           // 0..15 (s chunk of 32)
    size_t rowbase = ((size_t)b * S_ + (size_t)sc * 32) * D_ + t * 4;

    float4 acc = make_float4(0.f, 0.f, 0.f, 0.f);
    #pragma unroll 8
    for (int s = 0; s < 32; ++s) {
        float4 v = *(const float4*)(x + rowbase + (size_t)s * D_);
        acc.x += v.x; acc.y += v.y; acc.z += v.z; acc.w += v.w;
        __hip_bfloat16 h0 = __float2bfloat16(v.x);
        __hip_bfloat16 h1 = __float2bfloat16(v.y);
        __hip_bfloat16 h2 = __float2bfloat16(v.z);
        __hip_bfloat16 h3 = __float2bfloat16(v.w);
        ushort4 pk;
        pk.x = *(unsigned short*)&h0; pk.y = *(unsigned short*)&h1;
        pk.z = *(unsigned short*)&h2; pk.w = *(unsigned short*)&h3;
        *(ushort4*)((unsigned short*)xb + rowbase + (size_t)s * D_) = pk;
    }
    *(float4*)(partial + ((size_t)sc * B_ + b) * D_ + t * 4) = acc;
}

// ---------------- K2a: per-batch gating (16 blocks, d-parallel dot products) -----------
__global__ void k2a_logits(const float* __restrict__ partial,
                           const float* __restrict__ noise,
                           const float* __restrict__ w_gate,
                           const float* __restrict__ w_noise,
                           const float* __restrict__ thr_ptr,
                           float* __restrict__ gates_out,
                           float* __restrict__ clean_out,
                           float* __restrict__ std_out,
                           float* __restrict__ noisy_out,
                           float* __restrict__ thrin_out,
                           float* __restrict__ throut_out) {
    __shared__ float xm[D_];
    __shared__ float red[2][16][17];
    __shared__ float s_noisy[E_];

    int b = blockIdx.x, t = threadIdx.x;

    for (int d = t; d < D_; d += 256) {
        float s = 0.f;
        #pragma unroll
        for (int c = 0; c < 16; ++c) s += partial[((size_t)c * B_ + b) * D_ + d];
        xm[d] = s * (1.0f / S_);
    }
    __syncthreads();

    int e = t & 15, sl = t >> 4;
    const float* wg = w_gate  + (size_t)sl * 48 * E_ + e;
    const float* wn = w_noise + (size_t)sl * 48 * E_ + e;
    float cl = 0.f, nz = 0.f;
    #pragma unroll
    for (int i = 0; i < 48; ++i) {
        float xv = xm[sl * 48 + i];
        cl += xv * wg[(size_t)i * E_];
        nz += xv * wn[(size_t)i * E_];
    }
    red[0][sl][e] = cl;
    red[1][sl][e] = nz;
    __syncthreads();

    if (t < E_) {
        float c2 = 0.f, n2 = 0.f;
        #pragma unroll
        for (int s2 = 0; s2 < 16; ++s2) { c2 += red[0][s2][t]; n2 += red[1][s2][t]; }
        float sp     = fmaxf(n2, 0.f) + log1pf(expf(-fabsf(n2)));
        float stddev = sp + 0.01f;
        float ny     = c2 + noise[b * E_ + t] * stddev;
        s_noisy[t] = ny;
        clean_out[b * E_ + t] = c2;
        std_out[b * E_ + t]   = stddev;
        noisy_out[b * E_ + t] = ny;
    }
    __syncthreads();

    if (t < E_) {
        float ny = s_noisy[t];
        int rank = 0;
        #pragma unroll
        for (int j = 0; j < E_; ++j) {
            float vj = s_noisy[j];
            if (vj > ny || (vj == ny && j < t)) rank++;
        }
        if (rank == K_)     thrin_out[b]  = ny;
        if (rank == K_ - 1) throut_out[b] = ny;

        float mx = -1e30f;
        #pragma unroll
        for (int j = 0; j < E_; ++j) mx = fmaxf(mx, s_noisy[j]);
        float den = 0.f;
        #pragma unroll
        for (int j = 0; j < E_; ++j) den += expf(s_noisy[j] - mx);
        float gate = expf(ny - mx) / den;
        float sig  = 1.f / (1.f + expf(-thr_ptr[0]));
        gates_out[b * E_ + t] = fmaxf(gate - sig, 0.f);
    }
}

// ------- K3: Wb mix (blocks 0..575) + expert bias (576..623) + cv^2 loss (624) ---------
__global__ void k3_wb(const float* __restrict__ gates, const float* __restrict__ weight,
                      const float* __restrict__ bias,
                      const float* __restrict__ clean,
                      const float* __restrict__ stdv,
                      const float* __restrict__ noisyv,
                      const float* __restrict__ thrin,
                      const float* __restrict__ throut,
                      __hip_bfloat16* __restrict__ wb, float* __restrict__ ebias,
                      float* __restrict__ loss_out) {
    __shared__ float g[B_ * E_];
    int t = threadIdx.x;
    g[t] = gates[t];
    __syncthreads();

    if (blockIdx.x == 624) {                 // loss block
        __shared__ float s_imp[E_], s_load[E_];
        if (t < E_) {
            float imp = 0.f, ld = 0.f;
            #pragma unroll
            for (int bb = 0; bb < B_; ++bb) {
                imp += g[bb * E_ + t];
                float ti = thrin[bb], to = throut[bb];
                float c2 = clean[bb * E_ + t], sd = stdv[bb * E_ + t], nl = noisyv[bb * E_ + t];
                float z  = (nl > ti) ? (c2 - ti) / sd : (c2 - to) / sd;
                ld += 0.5f * erfcf(-z * 0.70710678118654752f);   // Phi(z)
            }
            s_imp[t]  = imp;
            s_load[t] = ld;
        }
        __syncthreads();
        if (t == 0) {
            float m1 = 0.f, m2 = 0.f;
            #pragma unroll
            for (int j = 0; j < E_; ++j) { m1 += s_imp[j]; m2 += s_load[j]; }
            m1 /= E_; m2 /= E_;
            float v1 = 0.f, v2 = 0.f;
            #pragma unroll
            for (int j = 0; j < E_; ++j) {
                float a = s_imp[j]  - m1; v1 += a * a;
                float c = s_load[j] - m2; v2 += c * c;
            }
            v1 /= (E_ - 1); v2 /= (E_ - 1);
            loss_out[0] = (v1 / (m1 * m1 + 1e-10f) + v2 / (m2 * m2 + 1e-10f)) * 0.01f;
        }
        return;
    }

    if (blockIdx.x >= 576) {                 // bias-mix tail blocks
        int idx = (blockIdx.x - 576) * 256 + t;
        int b = idx / D_, o = idx % D_;
        float acc = 0.f;
        #pragma unroll
        for (int e = 0; e < E_; ++e) acc += g[b * E_ + e] * bias[e * D_ + o];
        ebias[idx] = acc;
        return;
    }

    size_t base = ((size_t)blockIdx.x * 256 + t) * 4;
    float4 acc[B_];
    #pragma unroll
    for (int b = 0; b < B_; ++b) acc[b] = make_float4(0.f, 0.f, 0.f, 0.f);

    #pragma unroll
    for (int e = 0; e < E_; ++e) {
        float4 w4 = *(const float4*)(weight + (size_t)e * D_ * D_ + base);
        #pragma unroll
        for (int b = 0; b < B_; ++b) {
            float ge = g[b * E_ + e];
            acc[b].x += ge * w4.x; acc[b].y += ge * w4.y;
            acc[b].z += ge * w4.z; acc[b].w += ge * w4.w;
        }
    }
    #pragma unroll
    for (int b = 0; b < B_; ++b) {
        __hip_bfloat16 h0 = __float2bfloat16(acc[b].x);
        __hip_bfloat16 h1 = __float2bfloat16(acc[b].y);
        __hip_bfloat16 h2 = __float2bfloat16(acc[b].z);
        __hip_bfloat16 h3 = __float2bfloat16(acc[b].w);
        ushort4 pk;
        pk.x = *(unsigned short*)&h0; pk.y = *(unsigned short*)&h1;
        pk.z = *(unsigned short*)&h2; pk.w = *(unsigned short*)&h3;
        *(ushort4*)((unsigned short*)wb + (size_t)b * D_ * D_ + base) = pk;
    }
}

// ---------------- K4: batched GEMM, 128x192 tile, 8 waves, XCD-local b ------------------
#define BM 128
#define BN 192
#define BK 64
#define NT (D_ / BK)   // 12 K-tiles
// dynamic LDS: As[2][128][64] bf16 (32KB) then Bs[2][192][64] bf16 (48KB) = 80KB

__global__ __launch_bounds__(512) void k4_gemm(const __hip_bfloat16* __restrict__ xb,
                                               const __hip_bfloat16* __restrict__ wbm,
                                               const float* __restrict__ ebias,
                                               float* __restrict__ y) {
    extern __shared__ __hip_bfloat16 smem[];
    __hip_bfloat16* As = smem;                      // [2][BM][BK]
    __hip_bfloat16* Bs = smem + 2 * BM * BK;        // [2][BN][BK]
    #define AS(buf, r, c) As[((buf) * BM + (r)) * BK + (c)]
    #define BS(buf, r, c) Bs[((buf) * BN + (r)) * BK + (c)]

    int t = threadIdx.x;
    // XCD-aware decode: blocks with the same (wgid&7) land on the same XCD (round-robin).
    // Each XCD owns b in {2*xcd, 2*xcd+1}: working set 2*(xb[b] 786KB + wb[b] 1.18MB) < 4MB L2.
    int wgid  = blockIdx.x;        // 0..255
    int xcd   = wgid & 7;
    int local = wgid >> 3;         // 0..31
    int b  = (xcd << 1) | (local & 1);
    int r2 = local >> 1;           // 0..15
    int bm = r2 & 3;               // 0..3  (512/128)
    int bn = r2 >> 2;              // 0..3  (768/192)

    const __hip_bfloat16* xp = xb  + (size_t)b * S_ * D_ + (size_t)(bm * BM) * D_;
    const __hip_bfloat16* wp = wbm + (size_t)b * D_ * D_ + (size_t)(bn * BN) * D_;

    int wave = t >> 6, lane = t & 63;
    int wm = wave >> 2, wn = wave & 3;         // 2x4 waves, each 64x48 out
    int lrow = lane & 15;
    int lk   = (lane >> 4) << 3;               // 0,8,16,24

    int lr = lane >> 3;          // 0..7  (row within 8-row staging group)
    int lc = (lane & 7) * 8;     // element col 0..56

    f32x4 zero4 = {0.f, 0.f, 0.f, 0.f};
    f32x4 acc[4][3];
    #pragma unroll
    for (int m = 0; m < 4; ++m)
        #pragma unroll
        for (int n = 0; n < 3; ++n) acc[m][n] = zero4;

    // staging: wave w owns A rows [w*16, w*16+16) and B rows [w*24, w*24+24)
    #define STAGE(buf, k0)                                                          \
        do {                                                                        \
            _Pragma("unroll")                                                       \
            for (int i = 0; i < 2; ++i) {                                           \
                int r = wave * 16 + i * 8;                                          \
                GLOAD16(xp + (size_t)(r + lr) * D_ + (k0) + lc, &AS(buf, r, 0));    \
            }                                                                       \
            _Pragma("unroll")                                                       \
            for (int i = 0; i < 3; ++i) {                                           \
                int r = wave * 24 + i * 8;                                          \
                GLOAD16(wp + (size_t)(r + lr) * D_ + (k0) + lc, &BS(buf, r, 0));    \
            }                                                                       \
        } while (0)

    #define COMPUTE(buf)                                                            \
        do {                                                                        \
            _Pragma("unroll")                                                       \
            for (int kk = 0; kk < BK; kk += 32) {                                   \
                short8 afr[4], bfr[3];                                              \
                _Pragma("unroll")                                                   \
                for (int m = 0; m < 4; ++m)                                         \
                    afr[m] = *(const short8*)(&AS(buf, wm * 64 + m * 16 + lrow, kk + lk)); \
                _Pragma("unroll")                                                   \
                for (int n = 0; n < 3; ++n)                                         \
                    bfr[n] = *(const short8*)(&BS(buf, wn * 48 + n * 16 + lrow, kk + lk)); \
                _Pragma("unroll")                                                   \
                for (int m = 0; m < 4; ++m)                                         \
                    _Pragma("unroll")                                               \
                    for (int n = 0; n < 3; ++n)                                     \
                        acc[m][n] = __builtin_amdgcn_mfma_f32_16x16x32_bf16(        \
                            afr[m], bfr[n], acc[m][n], 0, 0, 0);                    \
            }                                                                       \
        } while (0)

    STAGE(0, 0);
    __syncthreads();                       // compiler drains vmcnt(0) before barrier
    int cur = 0;
    for (int kt = 0; kt < NT - 1; ++kt) {
        STAGE(cur ^ 1, (kt + 1) * BK);     // prefetch next tile, in flight during MFMA
        COMPUTE(cur);
        __syncthreads();
        cur ^= 1;
    }
    COMPUTE(cur);

    float* yp = y + (size_t)b * S_ * D_ + (size_t)(bm * BM) * D_ + bn * BN;
    const float* ep = ebias + (size_t)b * D_ + bn * BN;
    int crow = (lane >> 4) * 4;
    int ccol = lane & 15;
    #pragma unroll
    for (int n = 0; n < 3; ++n) {
        float eb = ep[wn * 48 + n * 16 + ccol];
        #pragma unroll
        for (int m = 0; m < 4; ++m) {
            #pragma unroll
            for (int j = 0; j < 4; ++j) {
                yp[(size_t)(wm * 64 + m * 16 + crow + j) * D_ + wn * 48 + n * 16 + ccol] =
                    acc[m][n][j] + eb;
            }
        }
    }
    #undef STAGE
    #undef COMPUTE
    #undef AS
    #undef BS
}

// -------------------------------------------------------------------------------------
extern "C" void kernel_launch(void* const* d_in, const int* in_sizes, int n_in,
                              void* d_out, int out_size, void* d_ws, size_t ws_size,
                              hipStream_t stream) {
    const float* x       = (const float*)d_in[0];
    const float* noise   = (const float*)d_in[1];
    const float* w_gate  = (const float*)d_in[2];
    const float* w_noise = (const float*)d_in[3];
    const float* thr     = (const float*)d_in[4];
    const float* weight  = (const float*)d_in[5];
    const float* bias    = (const float*)d_in[6];
    float* out = (float*)d_out;   // y [B*S*D] then loss [1]

    char* ws = (char*)d_ws;
    float*          partial = (float*)(ws + 0);               // 16*B*D f32 = 786432 B
    float*          gates   = (float*)(ws + 786432);
    float*          clean   = (float*)(ws + 787456);
    float*          stdv    = (float*)(ws + 788480);
    float*          noisyv  = (float*)(ws + 789504);
    float*          thrin   = (float*)(ws + 790528);
    float*          throut  = (float*)(ws + 790592);
    float*          ebias   = (float*)(ws + 790656);          // B*D f32
    __hip_bfloat16* xb      = (__hip_bfloat16*)(ws + 839808);     // B*S*D bf16
    __hip_bfloat16* wb      = (__hip_bfloat16*)(ws + 13422720);   // B*D*D bf16

    k1_mean_cvt<<<dim3(B_, 16), 192, 0, stream>>>(x, xb, partial);
    k2a_logits<<<16, 256, 0, stream>>>(partial, noise, w_gate, w_noise, thr, gates,
                                       clean, stdv, noisyv, thrin, throut);
    k3_wb<<<625, 256, 0, stream>>>(gates, weight, bias, clean, stdv, noisyv, thrin, throut,
                                   wb, ebias, out + (size_t)B_ * S_ * D_);
    k4_gemm<<<256, 512, 81920, stream>>>(xb, wb, ebias, out);
}